// Round 6
// baseline (163.036 us; speedup 1.0000x reference)
//
#include <hip/hip_runtime.h>
#include <hip/hip_fp16.h>

#define N_ROWS 8192
#define D_IN   4096
#define D_F    8192

// Radix-4 Hadamard butterfly over two index bits.
__device__ __forceinline__ void h4(float& a, float& b, float& c, float& d) {
  float t0 = a + b, t1 = a - b, t2 = c + d, t3 = c - d;
  a = t0 + t2; c = t0 - t2;
  b = t1 + t3; d = t1 - t3;
}

// DPP move: result lane gets source lane per CTRL (quad_perm / row ops).
template<int CTRL>
__device__ __forceinline__ float dppf(float v) {
  int iv = __builtin_bit_cast(int, v);
  int r = __builtin_amdgcn_update_dpp(0, iv, CTRL, 0xF, 0xF, true);
  return __builtin_bit_cast(float, r);
}

#define DPP_QUAD_XOR1       0xB1   // quad_perm(1,0,3,2)
#define DPP_QUAD_XOR2       0x4E   // quad_perm(2,3,0,1)
#define DPP_QUAD_XOR3       0x1B   // quad_perm(3,2,1,0)
#define DPP_ROW_HALF_MIRROR 0x141  // XOR 7 within 16-lane row
#define DPP_ROW_ROR8        0x128  // rotate 8 within row == XOR 8

__device__ __forceinline__ unsigned pk(float lo, float hi) {
  __half2 h = __floats2half2_rn(lo, hi);        // x=lo, y=hi
  return __builtin_bit_cast(unsigned, h);
}
__device__ __forceinline__ float2 upk(unsigned u) {
  return __half22float2(__builtin_bit_cast(__half2, u));
}

// One block = TWO rows (shared perm -> packed gather serves both).
// elem e = c*1024 + t*4 + i:  i=e[1:0], lane=e[7:2], wv=e[9:8], c=e[11:10]
//  - bits {0,1},{10,11}: register h4 (fp32)
//  - bits {2..7}: VALU cross-lane (DPP / permlane swaps), fp32 — zero LDS
//  - bits {8,9}: one b128 LDS RMW trip on PACKED f16x2 (unpack->fp32 h4->repack)
// z stored as u32 = (f16 row1)<<16 | f16 row0: stage/trip/gather LDS cost
// per row HALVES vs 1-row blocks. acc stays fp32 (64 regs) -> x re-fetched
// per degree (L3-hot) instead of held in registers.
// fp16 cost: exactly 2 roundings per z value -> ~0.3% worst-case output err.
__global__ __launch_bounds__(256, 3) void srht_kernel(
    const float* __restrict__ x,
    const float* __restrict__ rad,
    const int* __restrict__ perm,
    float* __restrict__ out)
{
  __shared__ __align__(16) unsigned zp[D_IN];   // 16 KiB packed f16x2
  const int t    = threadIdx.x;
  const int lane = t & 63;
  const int wv   = t >> 6;
  const int n0   = blockIdx.x * 2;

  const float sg0 = (lane & 1)  ? -1.f : 1.f;
  const float sg1 = (lane & 2)  ? -1.f : 1.f;
  const float sg2 = (lane & 4)  ? -1.f : 1.f;
  const float sg3 = (lane & 8)  ? -1.f : 1.f;
  const float sg4 = (lane & 16) ? -1.f : 1.f;
  const float sg5 = (lane & 32) ? -1.f : 1.f;

  const float INV = 0.01104854345603981f;  // 1/sqrt(8192)
  float acc0[32], acc1[32];
  #pragma unroll
  for (int k = 0; k < 32; ++k) { acc0[k] = INV; acc1[k] = INV; }

  // full fp32 FWHT of one row except bits {8,9}: load, rad-mul, reg h4s,
  // 6 lane-bit stages via DPP/permlane.
  auto compute_v = [&](const float4* xrow, const float4* rrow, float v[4][4]) {
    #pragma unroll
    for (int c = 0; c < 4; ++c) {
      float4 tv = xrow[c * 256 + t];
      float4 rv = rrow[c * 256 + t];
      v[c][0] = tv.x * rv.x;
      v[c][1] = tv.y * rv.y;
      v[c][2] = tv.z * rv.z;
      v[c][3] = tv.w * rv.w;
    }
    #pragma unroll
    for (int c = 0; c < 4; ++c) h4(v[c][0], v[c][1], v[c][2], v[c][3]);
    #pragma unroll
    for (int i = 0; i < 4; ++i) h4(v[0][i], v[1][i], v[2][i], v[3][i]);

    #pragma unroll
    for (int c = 0; c < 4; ++c)
      #pragma unroll
      for (int i = 0; i < 4; ++i) {     // XOR 1 (e-bit 2)
        float p = dppf<DPP_QUAD_XOR1>(v[c][i]);
        v[c][i] = fmaf(sg0, v[c][i], p);
      }
    #pragma unroll
    for (int c = 0; c < 4; ++c)
      #pragma unroll
      for (int i = 0; i < 4; ++i) {     // XOR 2 (e-bit 3)
        float p = dppf<DPP_QUAD_XOR2>(v[c][i]);
        v[c][i] = fmaf(sg1, v[c][i], p);
      }
    #pragma unroll
    for (int c = 0; c < 4; ++c)
      #pragma unroll
      for (int i = 0; i < 4; ++i) {     // XOR 4 (e-bit 4): XOR7 then XOR3
        float p = dppf<DPP_QUAD_XOR3>(dppf<DPP_ROW_HALF_MIRROR>(v[c][i]));
        v[c][i] = fmaf(sg2, v[c][i], p);
      }
    #pragma unroll
    for (int c = 0; c < 4; ++c)
      #pragma unroll
      for (int i = 0; i < 4; ++i) {     // XOR 8 (e-bit 5)
        float p = dppf<DPP_ROW_ROR8>(v[c][i]);
        v[c][i] = fmaf(sg3, v[c][i], p);
      }
    #pragma unroll
    for (int c = 0; c < 4; ++c)
      #pragma unroll
      for (int i = 0; i < 4; ++i) {     // XOR 16 (e-bit 6)
#if __has_builtin(__builtin_amdgcn_permlane16_swap)
        unsigned iv = __builtin_bit_cast(unsigned, v[c][i]);
        auto r = __builtin_amdgcn_permlane16_swap(iv, iv, false, false);
        float p = __builtin_bit_cast(float, (lane & 16) ? r[0] : r[1]);
#else
        float p = __shfl_xor(v[c][i], 16, 64);
#endif
        v[c][i] = fmaf(sg4, v[c][i], p);
      }
    #pragma unroll
    for (int c = 0; c < 4; ++c)
      #pragma unroll
      for (int i = 0; i < 4; ++i) {     // XOR 32 (e-bit 7)
#if __has_builtin(__builtin_amdgcn_permlane32_swap)
        unsigned iv = __builtin_bit_cast(unsigned, v[c][i]);
        auto r = __builtin_amdgcn_permlane32_swap(iv, iv, false, false);
        float p = __builtin_bit_cast(float, (lane & 32) ? r[0] : r[1]);
#else
        float p = __shfl_xor(v[c][i], 32, 64);
#endif
        v[c][i] = fmaf(sg5, v[c][i], p);
      }
  };

  uint4* z4 = reinterpret_cast<uint4*>(zp);
  const float4* x0 = reinterpret_cast<const float4*>(x) + (size_t)n0 * (D_IN / 4);
  const float4* x1 = x0 + (D_IN / 4);

  #pragma unroll 1
  for (int d = 0; d < 3; ++d) {
    const float4* rrow = reinterpret_cast<const float4*>(rad) + d * (D_IN / 4);
    float v0[4][4], v1[4][4];
    compute_v(x0, rrow, v0);
    compute_v(x1, rrow, v1);

    __syncthreads();   // previous degree's gather done reading zp
    // ---- stage: pack both rows, natural-layout b128 (conflict-free)
    #pragma unroll
    for (int c = 0; c < 4; ++c) {
      uint4 u;
      u.x = pk(v0[c][0], v1[c][0]);
      u.y = pk(v0[c][1], v1[c][1]);
      u.z = pk(v0[c][2], v1[c][2]);
      u.w = pk(v0[c][3], v1[c][3]);
      z4[c * 256 + t] = u;
    }
    __syncthreads();

    // ---- trip: bits {8,9} on packed values. Disjoint per-thread RMW sets.
    {
      float a0[4][4], a1[4][4];
      #pragma unroll
      for (int ww = 0; ww < 4; ++ww) {
        uint4 u = z4[wv * 256 + ww * 64 + lane];
        float2 f;
        f = upk(u.x); a0[ww][0] = f.x; a1[ww][0] = f.y;
        f = upk(u.y); a0[ww][1] = f.x; a1[ww][1] = f.y;
        f = upk(u.z); a0[ww][2] = f.x; a1[ww][2] = f.y;
        f = upk(u.w); a0[ww][3] = f.x; a1[ww][3] = f.y;
      }
      #pragma unroll
      for (int i = 0; i < 4; ++i) {
        h4(a0[0][i], a0[1][i], a0[2][i], a0[3][i]);
        h4(a1[0][i], a1[1][i], a1[2][i], a1[3][i]);
      }
      #pragma unroll
      for (int ww = 0; ww < 4; ++ww) {
        uint4 u;
        u.x = pk(a0[ww][0], a1[ww][0]);
        u.y = pk(a0[ww][1], a1[ww][1]);
        u.z = pk(a0[ww][2], a1[ww][2]);
        u.w = pk(a0[ww][3], a1[ww][3]);
        z4[wv * 256 + ww * 64 + lane] = u;
      }
    }
    __syncthreads();

    // ---- packed gather: one u32 read serves both rows
    const int4* p4 = reinterpret_cast<const int4*>(perm) + d * (D_F / 4);
    #pragma unroll
    for (int it = 0; it < 8; ++it) {
      int4 p = p4[it * 256 + t];
      float2 g0 = upk(zp[p.x]);
      float2 g1 = upk(zp[p.y]);
      float2 g2 = upk(zp[p.z]);
      float2 g3 = upk(zp[p.w]);
      acc0[it*4+0] *= g0.x; acc1[it*4+0] *= g0.y;
      acc0[it*4+1] *= g1.x; acc1[it*4+1] *= g1.y;
      acc0[it*4+2] *= g2.x; acc1[it*4+2] *= g2.y;
      acc0[it*4+3] *= g3.x; acc1[it*4+3] *= g3.y;
    }
  }

  // ---- coalesced float4 output, two rows
  float4* oa = reinterpret_cast<float4*>(out + (size_t)n0 * D_F);
  float4* ob = reinterpret_cast<float4*>(out + (size_t)(n0 + 1) * D_F);
  #pragma unroll
  for (int it = 0; it < 8; ++it) {
    oa[it * 256 + t] =
        make_float4(acc0[it*4+0], acc0[it*4+1], acc0[it*4+2], acc0[it*4+3]);
    ob[it * 256 + t] =
        make_float4(acc1[it*4+0], acc1[it*4+1], acc1[it*4+2], acc1[it*4+3]);
  }
}

extern "C" void kernel_launch(void* const* d_in, const int* in_sizes, int n_in,
                              void* d_out, int out_size, void* d_ws, size_t ws_size,
                              hipStream_t stream) {
  const float* x   = (const float*)d_in[0];
  const float* rad = (const float*)d_in[1];
  const int* perm  = (const int*)d_in[2];
  float* out       = (float*)d_out;
  srht_kernel<<<N_ROWS / 2, 256, 0, stream>>>(x, rad, perm, out);
}

// Round 8
// 130.594 us; speedup vs baseline: 1.2484x; 1.2484x over previous
//
#include <hip/hip_runtime.h>
#include <hip/hip_fp16.h>

#define N_ROWS 8192
#define D_IN   4096
#define D_F    8192

// Radix-4 Hadamard butterfly over two index bits.
__device__ __forceinline__ void h4(float& a, float& b, float& c, float& d) {
  float t0 = a + b, t1 = a - b, t2 = c + d, t3 = c - d;
  a = t0 + t2; c = t0 - t2;
  b = t1 + t3; d = t1 - t3;
}

// DPP move: result lane gets source lane per CTRL (quad_perm / row ops).
template<int CTRL>
__device__ __forceinline__ float dppf(float v) {
  int iv = __builtin_bit_cast(int, v);
  int r = __builtin_amdgcn_update_dpp(0, iv, CTRL, 0xF, 0xF, true);
  return __builtin_bit_cast(float, r);
}

#define DPP_QUAD_XOR1       0xB1   // quad_perm(1,0,3,2)
#define DPP_QUAD_XOR2       0x4E   // quad_perm(2,3,0,1)
#define DPP_QUAD_XOR3       0x1B   // quad_perm(3,2,1,0)
#define DPP_ROW_HALF_MIRROR 0x141  // XOR 7 within 16-lane row
#define DPP_ROW_ROR8        0x128  // rotate 8 within row == XOR 8

__device__ __forceinline__ unsigned pkrtz(float lo, float hi) {
#if __has_builtin(__builtin_amdgcn_cvt_pkrtz)
  auto h = __builtin_amdgcn_cvt_pkrtz(lo, hi);   // __fp16 ext_vector(2)
  return __builtin_bit_cast(unsigned, h);
#else
  __half2 h = __floats2half2_rn(lo, hi);
  return __builtin_bit_cast(unsigned, h);
#endif
}
__device__ __forceinline__ float2 upk(unsigned u) {
  return __half22float2(__builtin_bit_cast(__half2, u));
}

struct Sg { float s0, s1, s2, s3, s4, s5; };

// FWHT of one row over bits {0,1},{10,11} (reg h4) and {2..7} (DPP/permlane
// VALU cross-lane). Output: 16 fp32 in v[4][4]. Bits {8,9} left for the trip.
__device__ __forceinline__ void fwht_row(const float4* __restrict__ xrow,
                                         const float4* __restrict__ rrow,
                                         int t, int lane, const Sg& sg,
                                         float v[4][4]) {
  #pragma unroll
  for (int c = 0; c < 4; ++c) {
    float4 tv = xrow[c * 256 + t];
    float4 rv = rrow[c * 256 + t];
    v[c][0] = tv.x * rv.x;
    v[c][1] = tv.y * rv.y;
    v[c][2] = tv.z * rv.z;
    v[c][3] = tv.w * rv.w;
  }
  #pragma unroll
  for (int c = 0; c < 4; ++c) h4(v[c][0], v[c][1], v[c][2], v[c][3]);
  #pragma unroll
  for (int i = 0; i < 4; ++i) h4(v[0][i], v[1][i], v[2][i], v[3][i]);

  #pragma unroll
  for (int c = 0; c < 4; ++c)
    #pragma unroll
    for (int i = 0; i < 4; ++i) {     // XOR 1 (e-bit 2)
      float p = dppf<DPP_QUAD_XOR1>(v[c][i]);
      v[c][i] = fmaf(sg.s0, v[c][i], p);
    }
  #pragma unroll
  for (int c = 0; c < 4; ++c)
    #pragma unroll
    for (int i = 0; i < 4; ++i) {     // XOR 2 (e-bit 3)
      float p = dppf<DPP_QUAD_XOR2>(v[c][i]);
      v[c][i] = fmaf(sg.s1, v[c][i], p);
    }
  #pragma unroll
  for (int c = 0; c < 4; ++c)
    #pragma unroll
    for (int i = 0; i < 4; ++i) {     // XOR 4 (e-bit 4): XOR7 then XOR3
      float p = dppf<DPP_QUAD_XOR3>(dppf<DPP_ROW_HALF_MIRROR>(v[c][i]));
      v[c][i] = fmaf(sg.s2, v[c][i], p);
    }
  #pragma unroll
  for (int c = 0; c < 4; ++c)
    #pragma unroll
    for (int i = 0; i < 4; ++i) {     // XOR 8 (e-bit 5)
      float p = dppf<DPP_ROW_ROR8>(v[c][i]);
      v[c][i] = fmaf(sg.s3, v[c][i], p);
    }
  #pragma unroll
  for (int c = 0; c < 4; ++c)
    #pragma unroll
    for (int i = 0; i < 4; ++i) {     // XOR 16 (e-bit 6)
#if __has_builtin(__builtin_amdgcn_permlane16_swap)
      unsigned iv = __builtin_bit_cast(unsigned, v[c][i]);
      auto r = __builtin_amdgcn_permlane16_swap(iv, iv, false, false);
      float p = __builtin_bit_cast(float, (lane & 16) ? r[0] : r[1]);
#else
      float p = __shfl_xor(v[c][i], 16, 64);
#endif
      v[c][i] = fmaf(sg.s4, v[c][i], p);
    }
  #pragma unroll
  for (int c = 0; c < 4; ++c)
    #pragma unroll
    for (int i = 0; i < 4; ++i) {     // XOR 32 (e-bit 7)
#if __has_builtin(__builtin_amdgcn_permlane32_swap)
      unsigned iv = __builtin_bit_cast(unsigned, v[c][i]);
      auto r = __builtin_amdgcn_permlane32_swap(iv, iv, false, false);
      float p = __builtin_bit_cast(float, (lane & 32) ? r[0] : r[1]);
#else
      float p = __shfl_xor(v[c][i], 32, 64);
#endif
      v[c][i] = fmaf(sg.s5, v[c][i], p);
    }
}

// One degree, straight-line. zp: packed u32 = (f16 row1)<<16 | (f16 row0).
// Row0 packed to f16 pairs P0 IMMEDIATELY (its f32 regs die) before row1 is
// computed -> peak live ~ acc(64)+P0(8)+v1(16), no spill.
__device__ __forceinline__ void degree_step(
    int d, int t, int lane, int wv, const Sg& sg,
    const float4* __restrict__ x0, const float4* __restrict__ x1,
    const float* __restrict__ rad, const int* __restrict__ perm,
    unsigned* __restrict__ zp, float acc0[32], float acc1[32]) {
  const float4* rrow = reinterpret_cast<const float4*>(rad) + d * (D_IN / 4);
  uint4* z4 = reinterpret_cast<uint4*>(zp);

  // row0 -> f16 element-pairs: P0[2c]=(v[c][0],v[c][1]), P0[2c+1]=(v[c][2],v[c][3])
  unsigned P0[8];
  {
    float v[4][4];
    fwht_row(x0, rrow, t, lane, sg, v);
    #pragma unroll
    for (int c = 0; c < 4; ++c) {
      P0[2*c]   = pkrtz(v[c][0], v[c][1]);
      P0[2*c+1] = pkrtz(v[c][2], v[c][3]);
    }
  }
  float v1[4][4];
  fwht_row(x1, rrow, t, lane, sg, v1);

  __syncthreads();   // previous degree's gather has finished reading zp

  // merge rows byte-wise (v_perm) and stage, natural-layout b128
  #pragma unroll
  for (int c = 0; c < 4; ++c) {
    unsigned Qa = pkrtz(v1[c][0], v1[c][1]);
    unsigned Qb = pkrtz(v1[c][2], v1[c][3]);
    uint4 u;
    u.x = __builtin_amdgcn_perm(Qa, P0[2*c],   0x05040100u);
    u.y = __builtin_amdgcn_perm(Qa, P0[2*c],   0x07060302u);
    u.z = __builtin_amdgcn_perm(Qb, P0[2*c+1], 0x05040100u);
    u.w = __builtin_amdgcn_perm(Qb, P0[2*c+1], 0x07060302u);
    z4[c * 256 + t] = u;
  }
  __syncthreads();

  // trip: bits {8,9} on packed values; disjoint per-thread b128 RMW sets
  {
    float a0[4][4], a1[4][4];
    #pragma unroll
    for (int ww = 0; ww < 4; ++ww) {
      uint4 u = z4[wv * 256 + ww * 64 + lane];
      float2 f;
      f = upk(u.x); a0[ww][0] = f.x; a1[ww][0] = f.y;
      f = upk(u.y); a0[ww][1] = f.x; a1[ww][1] = f.y;
      f = upk(u.z); a0[ww][2] = f.x; a1[ww][2] = f.y;
      f = upk(u.w); a0[ww][3] = f.x; a1[ww][3] = f.y;
    }
    #pragma unroll
    for (int i = 0; i < 4; ++i) {
      h4(a0[0][i], a0[1][i], a0[2][i], a0[3][i]);
      h4(a1[0][i], a1[1][i], a1[2][i], a1[3][i]);
    }
    #pragma unroll
    for (int ww = 0; ww < 4; ++ww) {
      uint4 u;
      u.x = pkrtz(a0[ww][0], a1[ww][0]);
      u.y = pkrtz(a0[ww][1], a1[ww][1]);
      u.z = pkrtz(a0[ww][2], a1[ww][2]);
      u.w = pkrtz(a0[ww][3], a1[ww][3]);
      z4[wv * 256 + ww * 64 + lane] = u;
    }
  }
  __syncthreads();

  // packed gather: one u32 read serves both rows
  const int4* p4 = reinterpret_cast<const int4*>(perm) + d * (D_F / 4);
  #pragma unroll
  for (int it = 0; it < 8; ++it) {
    int4 p = p4[it * 256 + t];
    float2 g0 = upk(zp[p.x]);
    float2 g1 = upk(zp[p.y]);
    float2 g2 = upk(zp[p.z]);
    float2 g3 = upk(zp[p.w]);
    acc0[it*4+0] *= g0.x; acc1[it*4+0] *= g0.y;
    acc0[it*4+1] *= g1.x; acc1[it*4+1] *= g1.y;
    acc0[it*4+2] *= g2.x; acc1[it*4+2] *= g2.y;
    acc0[it*4+3] *= g3.x; acc1[it*4+3] *= g3.y;
  }
}

// One block = TWO rows (shared perm -> each packed-u32 LDS access serves both).
__global__ __launch_bounds__(256) void srht_kernel(
    const float* __restrict__ x,
    const float* __restrict__ rad,
    const int* __restrict__ perm,
    float* __restrict__ out)
{
  __shared__ __align__(16) unsigned zp[D_IN];   // 16 KiB packed f16x2
  const int t    = threadIdx.x;
  const int lane = t & 63;
  const int wv   = t >> 6;
  const int n0   = blockIdx.x * 2;

  Sg sg;
  sg.s0 = (lane & 1)  ? -1.f : 1.f;
  sg.s1 = (lane & 2)  ? -1.f : 1.f;
  sg.s2 = (lane & 4)  ? -1.f : 1.f;
  sg.s3 = (lane & 8)  ? -1.f : 1.f;
  sg.s4 = (lane & 16) ? -1.f : 1.f;
  sg.s5 = (lane & 32) ? -1.f : 1.f;

  const float INV = 0.01104854345603981f;  // 1/sqrt(8192)
  float acc0[32], acc1[32];
  #pragma unroll
  for (int k = 0; k < 32; ++k) { acc0[k] = INV; acc1[k] = INV; }

  const float4* x0 = reinterpret_cast<const float4*>(x) + (size_t)n0 * (D_IN / 4);
  const float4* x1 = x0 + (D_IN / 4);

  degree_step(0, t, lane, wv, sg, x0, x1, rad, perm, zp, acc0, acc1);
  degree_step(1, t, lane, wv, sg, x0, x1, rad, perm, zp, acc0, acc1);
  degree_step(2, t, lane, wv, sg, x0, x1, rad, perm, zp, acc0, acc1);

  // coalesced float4 output, two rows
  float4* oa = reinterpret_cast<float4*>(out + (size_t)n0 * D_F);
  float4* ob = reinterpret_cast<float4*>(out + (size_t)(n0 + 1) * D_F);
  #pragma unroll
  for (int it = 0; it < 8; ++it) {
    oa[it * 256 + t] =
        make_float4(acc0[it*4+0], acc0[it*4+1], acc0[it*4+2], acc0[it*4+3]);
    ob[it * 256 + t] =
        make_float4(acc1[it*4+0], acc1[it*4+1], acc1[it*4+2], acc1[it*4+3]);
  }
}

extern "C" void kernel_launch(void* const* d_in, const int* in_sizes, int n_in,
                              void* d_out, int out_size, void* d_ws, size_t ws_size,
                              hipStream_t stream) {
  const float* x   = (const float*)d_in[0];
  const float* rad = (const float*)d_in[1];
  const int* perm  = (const int*)d_in[2];
  float* out       = (float*)d_out;
  srht_kernel<<<N_ROWS / 2, 256, 0, stream>>>(x, rad, perm, out);
}